// Round 13
// baseline (38.349 us; speedup 1.0000x reference)
//
#include <hip/hip_runtime.h>
#include <math.h>

constexpr int BB = 2, NN = 4096, MM = 16384;
constexpr int JS = 32;                   // col strips (512 cols each)
constexpr int IG = 16;                   // row groups (256 rows each)
constexpr int SC = 512;                  // cols per strip
constexpr int ST = SC / 32;              // 16 B-tiles (32 cols) per strip
constexpr unsigned INFBITS = 0x7F800000u;
constexpr ushort ONEB = 0x3F80;          // bf16 1.0

typedef __attribute__((ext_vector_type(8)))  short  short8;
typedef __attribute__((ext_vector_type(8)))  ushort ushort8;
typedef __attribute__((ext_vector_type(16))) float  f32x16;

// sq = |s|^2 + |r|^2 - 2 s.r folded into ONE mfma_32x32x16_bf16 K-vector
// (hi/lo split, same pack words verified absmax 0.0 in R11/R12; K=16 fits the
// 13 used slots exactly — no more 19 zero-padded K slots):
//  A k0-7: {hi(-2s)xyz, hi(-2s)xyz, lo(-2s)xy}   k8-15: {lo(-2s)z, hi|s|2, lo|s|2, 1, 1, 0,0,0}
//  B k0-7: {hi(r)xyz,  lo(r)xyz,  hi(r)xy}      k8-15: {hi(r)z,  1, 1, hi|r|2, lo|r|2, 0,0,0}
// Fragment layout: lane = row/col (lane&31), K-half (lane>>5), 8 elems each.
// C layout (m74/m101-verified): col=lane&31, row=(reg&3)+8*(reg>>2)+4*(lane>>5).
__device__ __forceinline__ ushort f2bf(float f) {
    unsigned u = __float_as_uint(f);
    u += 0x7FFF + ((u >> 16) & 1);
    return (ushort)(u >> 16);
}
__device__ __forceinline__ void split2(float v, ushort& h, ushort& l) {
    h = f2bf(v);
    l = f2bf(v - __uint_as_float(((unsigned)h) << 16));
}
__device__ __forceinline__ float vmin16(const f32x16& c) {
    float a0 = fminf(fminf(c[0], c[1]),  fminf(c[2], c[3]));
    float a1 = fminf(fminf(c[4], c[5]),  fminf(c[6], c[7]));
    float a2 = fminf(fminf(c[8], c[9]),  fminf(c[10], c[11]));
    float a3 = fminf(fminf(c[12], c[13]), fminf(c[14], c[15]));
    return fminf(fminf(a0, a1), fminf(a2, a3));
}

__global__ __launch_bounds__(256, 4) void pair_kernel(
    const float* __restrict__ sampled,   // [BB][NN][4]
    const float* __restrict__ raw,       // [BB][MM][4]
    float* __restrict__ rowpart,         // [JS][BB][NN]
    float* __restrict__ colpart,         // [IG][BB][MM]
    unsigned* __restrict__ counter)      // zeroed here for the reduce kernel
{
    __shared__ ushort ldsB[ST * 512];    // 16 KB: tile jt at jt*512, frag-linear
    __shared__ float  ldsCol[4][SC];     // 8 KB per-wave col mins

    const int js = blockIdx.x, ig = blockIdx.y, b = blockIdx.z;
    const int tid = threadIdx.x, w = tid >> 6, lane = tid & 63;
    const int j0 = js * SC, i0 = ig * 256;

    if (js == 0 && ig == 0 && b == 0 && tid == 0) *counter = 0u;

    // ---- pack this strip's 512 raw points into LDS B-fragments ----
    const float4* rp4 = (const float4*)raw + (size_t)b * MM + j0;
    for (int t = tid; t < SC; t += 256) {
        float4 v = rp4[t];
        float n = fmaf(v.z, v.z, fmaf(v.y, v.y, v.x * v.x));
        ushort hx,lx,hy,ly,hz,lz,hn,ln;
        split2(v.x, hx, lx); split2(v.y, hy, ly);
        split2(v.z, hz, lz); split2(n, hn, ln);
        ushort* dst = ldsB + (t >> 5) * 512 + (t & 31) * 8;
        *(ushort8*)(dst)       = ushort8{hx,hy,hz,lx,ly,lz,hx,hy};   // K-half 0
        *(ushort8*)(dst + 256) = ushort8{hz,ONEB,ONEB,hn,ln,0,0,0};  // K-half 1
    }

    // ---- this wave's 2 A-fragments (rows i0 + w*64 .. +63) in registers ----
    short8 afr[2];
    const float4* sp4 = (const float4*)sampled + (size_t)b * NN + i0 + w * 64 + (lane & 31);
    const int half = lane >> 5;
#pragma unroll
    for (int f = 0; f < 2; ++f) {
        float4 v = sp4[f * 32];
        float n = fmaf(v.z, v.z, fmaf(v.y, v.y, v.x * v.x));
        ushort hx,lx,hy,ly,hz,lz,hn,ln;
        split2(-2.f * v.x, hx, lx); split2(-2.f * v.y, hy, ly);
        split2(-2.f * v.z, hz, lz); split2(n, hn, ln);
        ushort8 w0 = ushort8{hx,hy,hz,hx,hy,hz,lx,ly};
        ushort8 w1 = ushort8{lz,hn,ln,ONEB,ONEB,0,0,0};
        ushort8 sel = half ? w1 : w0;
        afr[f] = *(short8*)&sel;
    }
    __syncthreads();

    const float INF = __uint_as_float(INFBITS);
    float racc0[16], racc1[16];
#pragma unroll
    for (int r = 0; r < 16; ++r) { racc0[r] = INF; racc1[r] = INF; }

    const f32x16 zero = {0.f,0.f,0.f,0.f,0.f,0.f,0.f,0.f,
                         0.f,0.f,0.f,0.f,0.f,0.f,0.f,0.f};

#pragma unroll 1
    for (int jt = 0; jt < ST; ++jt) {
        short8 bf = *(const short8*)(ldsB + jt * 512 + lane * 8);
        f32x16 c0 = __builtin_amdgcn_mfma_f32_32x32x16_bf16(afr[0], bf, zero, 0, 0, 0);
        f32x16 c1 = __builtin_amdgcn_mfma_f32_32x32x16_bf16(afr[1], bf, zero, 0, 0, 0);
#pragma unroll
        for (int r = 0; r < 16; ++r) {
            racc0[r] = fminf(racc0[r], c0[r]);
            racc1[r] = fminf(racc1[r], c1[r]);
        }
        float m = fminf(vmin16(c0), vmin16(c1));      // min over 64 rows (lane's col)
        m = fminf(m, __shfl_xor(m, 32, 64));          // combine the two row-halves
        if (lane < 32) ldsCol[w][jt * 32 + lane] = m; // each slot written once
    }

    // ---- row mins: butterfly across the 32 cols (lane&31), plain stores ----
#pragma unroll
    for (int mask = 1; mask < 32; mask <<= 1) {
#pragma unroll
        for (int r = 0; r < 16; ++r) {
            racc0[r] = fminf(racc0[r], __shfl_xor(racc0[r], mask, 64));
            racc1[r] = fminf(racc1[r], __shfl_xor(racc1[r], mask, 64));
        }
    }
    if ((lane & 31) == 0) {                            // lanes 0 and 32
        float* rp = rowpart + ((size_t)js * BB + b) * NN + i0 + w * 64;
#pragma unroll
        for (int r = 0; r < 16; ++r) {
            const int row = (r & 3) + 8 * (r >> 2) + 4 * half;
            rp[row]      = fmaxf(racc0[r], 0.f);
            rp[32 + row] = fmaxf(racc1[r], 0.f);
        }
    }

    // ---- col mins: combine 4 waves, plain store ----
    __syncthreads();
    float* cp = colpart + ((size_t)ig * BB + b) * MM + j0;
    for (int t = tid; t < SC; t += 256) {
        float v = fminf(fminf(ldsCol[0][t], ldsCol[1][t]),
                        fminf(ldsCol[2][t], ldsCol[3][t]));
        cp[t] = fmaxf(v, 0.f);
    }
}

// 128 blocks; last block to finish combines the 128 partials and writes out.
__global__ __launch_bounds__(256) void reduce_kernel(
    const float* __restrict__ rowpart,
    const float* __restrict__ colpart,
    float* __restrict__ part,            // [128][3]
    unsigned* __restrict__ counter,
    float* __restrict__ out)
{
    const int k = blockIdx.x, b = k >> 6, s = k & 63;
    const int tid = threadIdx.x;
    const float INF = __uint_as_float(INFBITS);

    const int col = s * 256 + tid;
    float v = INF;
#pragma unroll 4
    for (int ig = 0; ig < IG; ++ig)
        v = fminf(v, colpart[((size_t)ig * BB + b) * MM + col]);
    float sB = sqrtf(v);

    const int row = s * 64 + (tid & 63);
    const int jq  = tid >> 6;
    float wv2 = INF;
#pragma unroll
    for (int q = 0; q < JS / 4; ++q)
        wv2 = fminf(wv2, rowpart[((size_t)(jq * (JS / 4) + q) * BB + b) * NN + row]);
    __shared__ float rred[4][64];
    rred[jq][tid & 63] = wv2;
    __syncthreads();
    float sF = 0.f, mF = 0.f;
    if (tid < 64) {
        float rmn = fminf(fminf(rred[0][tid], rred[1][tid]),
                          fminf(rred[2][tid], rred[3][tid]));
        float d = sqrtf(rmn);
        sF = d; mF = d;
    }

    for (int m = 1; m < 64; m <<= 1) {
        sB += __shfl_xor(sB, m, 64);
        sF += __shfl_xor(sF, m, 64);
        mF = fmaxf(mF, __shfl_xor(mF, m, 64));
    }
    __shared__ float red[3][4];
    const int lane = tid & 63, wvi = tid >> 6;
    if (lane == 0) { red[0][wvi] = sB; red[1][wvi] = sF; red[2][wvi] = mF; }
    __syncthreads();

    __shared__ bool isLast;
    if (tid == 0) {
        part[k * 3 + 0] = red[0][0] + red[0][1] + red[0][2] + red[0][3];
        part[k * 3 + 1] = red[1][0] + red[1][1] + red[1][2] + red[1][3];
        part[k * 3 + 2] = fmaxf(fmaxf(red[2][0], red[2][1]),
                                fmaxf(red[2][2], red[2][3]));
        __threadfence();                           // release partials device-wide
        isLast = (atomicAdd(counter, 1u) == 127u); // device-scope (m20)
    }
    __syncthreads();
    if (!isLast) return;

    __threadfence();                               // acquire
    volatile const float* vp = part;               // bypass L1 (stale-line guard)
    float fB = 0.f, fF = 0.f, fM = 0.f;
    if (tid < 128) {                               // wave0 -> b0, wave1 -> b1
        fB = vp[tid * 3 + 0]; fF = vp[tid * 3 + 1]; fM = vp[tid * 3 + 2];
    }
    for (int m = 1; m < 64; m <<= 1) {
        fB += __shfl_xor(fB, m, 64);
        fF += __shfl_xor(fF, m, 64);
        fM = fmaxf(fM, __shfl_xor(fM, m, 64));
    }
    __shared__ float fin[2][3];
    if (tid < 128 && (tid & 63) == 0) {
        fin[tid >> 6][0] = fB; fin[tid >> 6][1] = fF; fin[tid >> 6][2] = fM;
    }
    __syncthreads();
    if (tid == 0) {
        float l0 = 5.f * fin[0][0] / (float)MM + fin[0][1] / (float)NN + fin[0][2];
        float l1 = 5.f * fin[1][0] / (float)MM + fin[1][1] / (float)NN + fin[1][2];
        *out = 0.5f * (l0 + l1);
    }
}

extern "C" void kernel_launch(void* const* d_in, const int* in_sizes, int n_in,
                              void* d_out, int out_size, void* d_ws, size_t ws_size,
                              hipStream_t stream) {
    const float* sampled = (const float*)d_in[0];
    const float* raw     = (const float*)d_in[1];
    float* rowpart = (float*)d_ws;                          // JS*BB*NN = 1 MB
    float* colpart = rowpart + (size_t)JS * BB * NN;        // IG*BB*MM = 2 MB
    float* part    = colpart + (size_t)IG * BB * MM;        // 384 floats
    unsigned* counter = (unsigned*)(part + 3 * 128);
    float* out     = (float*)d_out;

    pair_kernel<<<dim3(JS, IG, BB), 256, 0, stream>>>(sampled, raw, rowpart, colpart, counter);
    reduce_kernel<<<128, 256, 0, stream>>>(rowpart, colpart, part, counter, out);
}